// Round 11
// baseline (50420.581 us; speedup 1.0000x reference)
//
#include <hip/hip_runtime.h>
#include <hip/hip_bf16.h>
#include <stdint.h>

#define NTOK 32768
#define DIM  768
#define KCB  4096
#define BM   128
#define BN   128
#define BKK  64
#define HALFK (KCB / 2)        // 2048 codes per half
#define NCH  (HALFK / BN)      // 16 chunks per half
#define NKB  (DIM / BKK)       // 12 K-steps per chunk
#define THREADS 512
#define TAU  1.5e-3f
#define CAP  12

typedef __attribute__((ext_vector_type(8))) short bf16x8;
typedef __attribute__((ext_vector_type(4))) float f32x4;

__device__ inline unsigned short f2bf(float f) {
    uint32_t u = __float_as_uint(f);
    uint32_t r = (u + 0x7fffu + ((u >> 16) & 1u)) >> 16;
    return (unsigned short)r;
}

__device__ inline void gload_lds16(const void* g, void* l) {
    __builtin_amdgcn_global_load_lds((const __attribute__((address_space(1))) void*)g,
                                     (__attribute__((address_space(3))) void*)l, 16, 0, 0);
}

// K0: X -> bf16 stash (upper half of each token's out slot), codebook -> bf16 in ws.
__global__ void vq_convert(const float* __restrict__ X, const float* __restrict__ E,
                           unsigned short* __restrict__ Xbf, unsigned short* __restrict__ Ebf,
                           unsigned int* __restrict__ counts, double* __restrict__ loss_sum,
                           unsigned int* __restrict__ ovf_cnt) {
    if (blockIdx.x == 0) {
        for (int k = threadIdx.x; k < KCB; k += 256) counts[k] = 0u;
        if (threadIdx.x == 0) { *loss_sum = 0.0; *ovf_cnt = 0u; }
    }
    int tid = blockIdx.x * blockDim.x + threadIdx.x;
    int nth = gridDim.x * blockDim.x;
    int totX = NTOK * DIM / 4;
    for (int i = tid; i < totX; i += nth) {
        float4 v = ((const float4*)X)[i];
        int e0 = i * 4;
        int t = e0 / DIM;
        int d = e0 - t * DIM;
        ushort4 o;
        o.x = f2bf(v.x); o.y = f2bf(v.y); o.z = f2bf(v.z); o.w = f2bf(v.w);
        *(ushort4*)&Xbf[(size_t)t * 1536 + 768 + d] = o;   // byte off: t*3072 + 1536 + 2d
    }
    int totE = KCB * DIM / 4;
    for (int i = tid; i < totE; i += nth) {
        float4 v = ((const float4*)E)[i];
        ushort4 o;
        o.x = f2bf(v.x); o.y = f2bf(v.y); o.z = f2bf(v.z); o.w = f2bf(v.w);
        *(ushort4*)&Ebf[(size_t)i * 4] = o;
    }
}

// K1: split-K main. 512 blocks = 256 token-groups x 2 codebook halves.
// m97 structure: single-buffered LDS (44 KB -> 2 blocks/CU), plain syncthreads.
// Output: per-(token,half) shortlist scratch in the token's out-slot lower half.
__global__ __launch_bounds__(THREADS, 4) void vq_main(
    const unsigned short* __restrict__ Xbf, const unsigned short* __restrict__ Ebf,
    float* __restrict__ out)
{
    __shared__ unsigned short As[BM * BKK];   // 16 KB, swizzled
    __shared__ unsigned short Bs[BN * BKK];   // 16 KB, swizzled
    __shared__ float rowmin4[BM * 4];         // 2 KB
    __shared__ float runmin[BM];
    __shared__ int   cnt[BM];
    __shared__ float candd[BM * CAP];         // 6 KB
    __shared__ unsigned short candk[BM * CAP];// 3 KB

    const int tid = threadIdx.x;
    const int wid = tid >> 6;
    const int lane = tid & 63;
    const int wm = wid >> 2;     // 0..1  (64-token row band)
    const int wn = wid & 3;      // 0..3  (32-code col band)
    const int g = blockIdx.x >> 1;
    const int half = blockIdx.x & 1;
    const int t0 = g * BM;
    const int kofs = half * HALFK;
    const int l15 = lane & 15;
    const int lhi = lane >> 4;

    if (tid < BM) { runmin[tid] = 3.0e38f; cnt[tid] = 0; }
    __syncthreads();

    for (int ci = 0; ci < NCH; ++ci) {
        f32x4 acc[4][2];
        #pragma unroll
        for (int mi = 0; mi < 4; ++mi)
            #pragma unroll
            for (int ni = 0; ni < 2; ++ni) { f32x4 z = {0.f,0.f,0.f,0.f}; acc[mi][ni] = z; }

        const int c0 = ci * BN;   // local code offset within this half

        for (int kb = 0; kb < NKB; ++kb) {
            const int kbb = kb * 128;   // byte offset within a 768-elem bf16 row
            // ---- stage (pre-swizzled global source, linear LDS dest): 4 loads/thread ----
            #pragma unroll
            for (int p = 0; p < 2; ++p) {
                int o = p * 8192 + tid * 16;
                int row = o >> 7, col = o & 127;
                int colsw = col ^ ((row & 7) << 4);
                const char* srcA = (const char*)Xbf + (size_t)(t0 + row) * 3072 + 1536 + kbb + colsw;
                gload_lds16(srcA, (char*)As + o);
                const char* srcB = (const char*)Ebf + (size_t)(kofs + c0 + row) * 1536 + kbb + colsw;
                gload_lds16(srcB, (char*)Bs + o);
            }
            __syncthreads();   // drains vmcnt(0); inter-block overlap hides this (2 blocks/CU)

            #pragma unroll
            for (int ks = 0; ks < 2; ++ks) {
                const int colbase = ks * 64 + lhi * 16;
                bf16x8 a[4], b[2];
                #pragma unroll
                for (int mi = 0; mi < 4; ++mi) {
                    int row = wm * 64 + mi * 16 + l15;
                    int byteoff = row * 128 + (colbase ^ ((row & 7) << 4));
                    a[mi] = *(const bf16x8*)((const char*)As + byteoff);
                }
                #pragma unroll
                for (int ni = 0; ni < 2; ++ni) {
                    int row = wn * 32 + ni * 16 + l15;
                    int byteoff = row * 128 + (colbase ^ ((row & 7) << 4));
                    b[ni] = *(const bf16x8*)((const char*)Bs + byteoff);
                }
                #pragma unroll
                for (int mi = 0; mi < 4; ++mi)
                    #pragma unroll
                    for (int ni = 0; ni < 2; ++ni)
                        acc[mi][ni] = __builtin_amdgcn_mfma_f32_16x16x32_bf16(a[mi], b[ni], acc[mi][ni], 0, 0, 0);
            }
            __syncthreads();   // all reads done -> next stage may overwrite
        }

        // ---- epilogue for this 128-code chunk ----
        #pragma unroll
        for (int mi = 0; mi < 4; ++mi) {
            #pragma unroll
            for (int r = 0; r < 4; ++r) {
                float v = fminf(-2.0f * acc[mi][0][r], -2.0f * acc[mi][1][r]);
                v = fminf(v, __shfl_xor(v, 1, 16));
                v = fminf(v, __shfl_xor(v, 2, 16));
                v = fminf(v, __shfl_xor(v, 4, 16));
                v = fminf(v, __shfl_xor(v, 8, 16));
                if (l15 == 0) {
                    int row = wm * 64 + mi * 16 + lhi * 4 + r;
                    rowmin4[row * 4 + wn] = v;
                }
            }
        }
        __syncthreads();
        if (tid < BM) {
            float m = fminf(fminf(rowmin4[tid*4], rowmin4[tid*4+1]),
                            fminf(rowmin4[tid*4+2], rowmin4[tid*4+3]));
            runmin[tid] = fminf(runmin[tid], m);
        }
        __syncthreads();
        float rm[4][4];
        #pragma unroll
        for (int mi = 0; mi < 4; ++mi)
            #pragma unroll
            for (int r = 0; r < 4; ++r)
                rm[mi][r] = runmin[wm * 64 + mi * 16 + lhi * 4 + r];
        #pragma unroll
        for (int mi = 0; mi < 4; ++mi)
            #pragma unroll
            for (int ni = 0; ni < 2; ++ni)
                #pragma unroll
                for (int r = 0; r < 4; ++r) {
                    float d = -2.0f * acc[mi][ni][r];
                    if (d <= rm[mi][r] + TAU) {
                        int row = wm * 64 + mi * 16 + lhi * 4 + r;
                        int slot = atomicAdd(&cnt[row], 1);
                        if (slot < CAP) {
                            candd[row * CAP + slot] = d;
                            candk[row * CAP + slot] = (unsigned short)(kofs + c0 + wn * 32 + ni * 16 + l15);
                        }
                    }
                }
        __syncthreads();
    }

    // ---- write per-(token,half) scratch into out-slot lower half (bytes [half*768, half*768+80)) ----
    if (tid < BM) {
        int tok = t0 + tid;
        float* base = out + (size_t)tok * DIM + half * 192;
        base[0] = runmin[tid];
        ((int*)base)[1] = cnt[tid];
        #pragma unroll
        for (int s = 0; s < CAP; ++s) base[2 + s] = candd[tid * CAP + s];
        unsigned short* ck = (unsigned short*)(base + 14);
        #pragma unroll
        for (int s = 0; s < CAP; ++s) ck[s] = candk[tid * CAP + s];
    }
}

// K2: merge halves, survivor filter, fp64 rescue, outputs. One wave per token.
__global__ __launch_bounds__(THREADS) void vq_final(
    const float* __restrict__ X, const float* __restrict__ Ecb,
    float* __restrict__ out,
    unsigned int* __restrict__ counts, double* __restrict__ loss_sum,
    unsigned int* __restrict__ ovf_cnt, int* __restrict__ ovf_list)
{
    const int wid = threadIdx.x >> 6;
    const int lane = threadIdx.x & 63;
    const int t0 = blockIdx.x * BM;

    for (int i = 0; i < 16; ++i) {
        int tok = t0 + wid * 16 + i;
        const float* b0 = out + (size_t)tok * DIM;
        const float* b1 = b0 + 192;
        float rm = fminf(b0[0], b1[0]);
        int n0 = ((const int*)b0)[1];
        int n1 = ((const int*)b1)[1];
        if (n0 > CAP || n1 > CAP) {
            if (lane == 0) {
                unsigned idx = atomicAdd(ovf_cnt, 1u);
                ovf_list[idx] = tok;
            }
            continue;
        }
        // survivor scan over both lists (lane-uniform broadcast reads)
        int surv = 0, onlyk = 0;
        for (int s = 0; s < n0; ++s)
            if (b0[2 + s] <= rm + TAU) { ++surv; onlyk = ((const unsigned short*)(b0 + 14))[s]; }
        for (int s = 0; s < n1; ++s)
            if (b1[2 + s] <= rm + TAU) { ++surv; onlyk = ((const unsigned short*)(b1 + 14))[s]; }

        const float4* Xr = (const float4*)&X[(size_t)tok * DIM];
        float4 xv[3];
        #pragma unroll
        for (int j = 0; j < 3; ++j) xv[j] = Xr[j * 64 + lane];

        int bestk;
        if (surv == 1) {
            bestk = onlyk;   // provably the fp32 argmin (all others > TAU - bf16 bound away)
        } else {
            double x2 = 0.0;
            #pragma unroll
            for (int j = 0; j < 3; ++j)
                x2 += (double)xv[j].x * xv[j].x + (double)xv[j].y * xv[j].y
                    + (double)xv[j].z * xv[j].z + (double)xv[j].w * xv[j].w;
            for (int off = 32; off; off >>= 1) x2 += __shfl_down(x2, off);
            x2 = __shfl(x2, 0);
            float x2f = (float)x2;
            float bestt = 3.0e38f; int bk = 1 << 30;
            for (int h = 0; h < 2; ++h) {
                const float* bh = h ? b1 : b0;
                int nh = h ? n1 : n0;
                for (int s = 0; s < nh; ++s) {
                    float dd = bh[2 + s];
                    if (dd > rm + TAU) continue;
                    int k = ((const unsigned short*)(bh + 14))[s];
                    const float4* er = (const float4*)&Ecb[(size_t)k * DIM];
                    double dot = 0.0, e2 = 0.0;
                    #pragma unroll
                    for (int j = 0; j < 3; ++j) {
                        float4 ev = er[j * 64 + lane];
                        dot += (double)xv[j].x * ev.x + (double)xv[j].y * ev.y
                             + (double)xv[j].z * ev.z + (double)xv[j].w * ev.w;
                        e2  += (double)ev.x * ev.x + (double)ev.y * ev.y
                             + (double)ev.z * ev.z + (double)ev.w * ev.w;
                    }
                    for (int off = 32; off; off >>= 1) { dot += __shfl_down(dot, off); e2 += __shfl_down(e2, off); }
                    dot = __shfl(dot, 0); e2 = __shfl(e2, 0);
                    float t = x2f - 2.0f * (float)dot;   // reference's fp32 rounding sequence
                    t = t + (float)e2;
                    if (t < bestt || (t == bestt && k < bk)) { bestt = t; bk = k; }
                }
            }
            bestk = bk;
        }
        const float4* q = (const float4*)&Ecb[(size_t)bestk * DIM];
        float4* outr = (float4*)&out[(size_t)tok * DIM];
        double sq = 0.0;
        #pragma unroll
        for (int j = 0; j < 3; ++j) {
            float4 qv = q[j * 64 + lane];
            outr[j * 64 + lane] = qv;
            double d0 = (double)qv.x - xv[j].x, d1 = (double)qv.y - xv[j].y;
            double d2 = (double)qv.z - xv[j].z, d3 = (double)qv.w - xv[j].w;
            sq += d0 * d0 + d1 * d1 + d2 * d2 + d3 * d3;
        }
        for (int off = 32; off; off >>= 1) sq += __shfl_down(sq, off);
        if (lane == 0) {
            out[(size_t)NTOK * DIM + tok] = (float)bestk;
            atomicAdd(&counts[bestk], 1u);
            atomicAdd(loss_sum, sq);
        }
    }
}

// K3: brute-force rescue for shortlist-overflow tokens (expected ~0)
__global__ void vq_overflow(const float* __restrict__ X, const float* __restrict__ Ecb,
                            float* __restrict__ out, unsigned int* __restrict__ counts,
                            double* __restrict__ loss_sum,
                            const unsigned int* __restrict__ ovf_cnt, const int* __restrict__ ovf_list)
{
    __shared__ float xrow[DIM];
    __shared__ float bt[256];
    __shared__ int bk[256];
    __shared__ double red[256];
    int n = (int)*ovf_cnt;
    for (int ti = blockIdx.x; ti < n; ti += gridDim.x) {
        int tok = ovf_list[ti];
        for (int d = threadIdx.x; d < DIM; d += 256) xrow[d] = X[(size_t)tok * DIM + d];
        __syncthreads();
        double p = 0.0;
        for (int d = threadIdx.x; d < DIM; d += 256) p += (double)xrow[d] * xrow[d];
        red[threadIdx.x] = p; __syncthreads();
        for (int s = 128; s; s >>= 1) { if (threadIdx.x < s) red[threadIdx.x] += red[threadIdx.x + s]; __syncthreads(); }
        float x2f = (float)red[0];
        __syncthreads();
        float bestt = 3.0e38f; int bestk = 1 << 30;
        for (int k = threadIdx.x; k < KCB; k += 256) {
            const float* er = &Ecb[(size_t)k * DIM];
            double dot = 0.0, e2 = 0.0;
            for (int d = 0; d < DIM; ++d) { double ev = er[d]; dot += (double)xrow[d] * ev; e2 += ev * ev; }
            float t = x2f - 2.0f * (float)dot;
            t = t + (float)e2;
            if (t < bestt || (t == bestt && k < bestk)) { bestt = t; bestk = k; }
        }
        bt[threadIdx.x] = bestt; bk[threadIdx.x] = bestk; __syncthreads();
        for (int s = 128; s; s >>= 1) {
            if (threadIdx.x < s) {
                float t2 = bt[threadIdx.x + s]; int k2 = bk[threadIdx.x + s];
                if (t2 < bt[threadIdx.x] || (t2 == bt[threadIdx.x] && k2 < bk[threadIdx.x])) {
                    bt[threadIdx.x] = t2; bk[threadIdx.x] = k2;
                }
            }
            __syncthreads();
        }
        int kwin = bk[0];
        double sq = 0.0;
        for (int d = threadIdx.x; d < DIM; d += 256) {
            float qv = Ecb[(size_t)kwin * DIM + d];
            out[(size_t)tok * DIM + d] = qv;
            double dlt = (double)qv - (double)xrow[d];
            sq += dlt * dlt;
        }
        red[threadIdx.x] = sq; __syncthreads();
        for (int s = 128; s; s >>= 1) { if (threadIdx.x < s) red[threadIdx.x] += red[threadIdx.x + s]; __syncthreads(); }
        if (threadIdx.x == 0) {
            out[(size_t)NTOK * DIM + tok] = (float)kwin;
            atomicAdd(&counts[kwin], 1u);
            atomicAdd(loss_sum, red[0]);
        }
        __syncthreads();
    }
}

// K4: scalars (loss/commitment/codebook/perplexity/usage)
__global__ void vq_stats(const unsigned int* __restrict__ counts, const double* __restrict__ loss_sum,
                         float* __restrict__ out)
{
    __shared__ double hred[256];
    __shared__ int ured[256];
    double h = 0.0; int used = 0;
    for (int k = threadIdx.x; k < KCB; k += 256) {
        unsigned c = counts[k];
        double pr = (double)c / (double)NTOK;
        h -= pr * log(pr + 1e-10);
        used += (c > 0) ? 1 : 0;
    }
    hred[threadIdx.x] = h; ured[threadIdx.x] = used; __syncthreads();
    for (int s = 128; s; s >>= 1) {
        if (threadIdx.x < s) { hred[threadIdx.x] += hred[threadIdx.x + s]; ured[threadIdx.x] += ured[threadIdx.x + s]; }
        __syncthreads();
    }
    if (threadIdx.x == 0) {
        double S = *loss_sum;
        double mse = S / ((double)NTOK * (double)DIM);
        size_t base = (size_t)NTOK * DIM + NTOK;
        out[base + 0] = (float)(mse * 1.25);   // loss = codebook + 0.25*commitment
        out[base + 1] = (float)mse;            // commitment_loss
        out[base + 2] = (float)mse;            // codebook_loss
        out[base + 3] = (float)exp(hred[0]);   // perplexity
        out[base + 4] = (float)((double)ured[0] / (double)KCB);  // usage_rate
    }
}

extern "C" void kernel_launch(void* const* d_in, const int* in_sizes, int n_in,
                              void* d_out, int out_size, void* d_ws, size_t ws_size,
                              hipStream_t stream) {
    const float* X = (const float*)d_in[0];
    const float* E = (const float*)d_in[1];
    float* out = (float*)d_out;
    char* ws = (char*)d_ws;
    unsigned short* Ebf = (unsigned short*)ws;                 // 6,291,456 B
    unsigned int* counts = (unsigned int*)(ws + 6291456);      // 16,384 B
    double* loss_sum = (double*)(ws + 6307840);                // 8 B
    unsigned int* ovf_cnt = (unsigned int*)(ws + 6307848);     // 4 B (+4 pad)
    int* ovf_list = (int*)(ws + 6307856);                      // 131,072 B
    unsigned short* Xbf = (unsigned short*)d_out;              // bf16 stash in out-slot upper halves

    vq_convert<<<2048, 256, 0, stream>>>(X, E, Xbf, Ebf, counts, loss_sum, ovf_cnt);
    vq_main<<<2 * (NTOK / BM), THREADS, 0, stream>>>(Xbf, Ebf, out);
    vq_final<<<NTOK / BM, THREADS, 0, stream>>>(X, E, out, counts, loss_sum, ovf_cnt, ovf_list);
    vq_overflow<<<16, 256, 0, stream>>>(X, E, out, counts, loss_sum, ovf_cnt, ovf_list);
    vq_stats<<<1, 256, 0, stream>>>(counts, loss_sum, out);
}

// Round 12
// 907.561 us; speedup vs baseline: 55.5562x; 55.5562x over previous
//
#include <hip/hip_runtime.h>
#include <hip/hip_bf16.h>
#include <stdint.h>

#define NTOK 32768
#define DIM  768
#define KCB  4096
#define BM   128
#define BN   128
#define BKK  64
#define HALFK (KCB / 2)        // 2048 codes per half
#define NCH  (HALFK / BN)      // 16 chunks per half
#define NKB  (DIM / BKK)       // 12 K-steps per chunk
#define THREADS 512
#define TAU  1.5e-3f
#define CAP  24

typedef __attribute__((ext_vector_type(8))) short bf16x8;
typedef __attribute__((ext_vector_type(4))) float f32x4;

__device__ inline unsigned short f2bf(float f) {
    uint32_t u = __float_as_uint(f);
    uint32_t r = (u + 0x7fffu + ((u >> 16) & 1u)) >> 16;
    return (unsigned short)r;
}

__device__ inline void gload_lds16(const void* g, void* l) {
    __builtin_amdgcn_global_load_lds((const __attribute__((address_space(1))) void*)g,
                                     (__attribute__((address_space(3))) void*)l, 16, 0, 0);
}

// K0: X -> bf16 stash (upper half of each token's out slot), codebook -> bf16 in ws.
__global__ void vq_convert(const float* __restrict__ X, const float* __restrict__ E,
                           unsigned short* __restrict__ Xbf, unsigned short* __restrict__ Ebf,
                           unsigned int* __restrict__ counts, double* __restrict__ loss_sum,
                           unsigned int* __restrict__ ovf_cnt) {
    if (blockIdx.x == 0) {
        for (int k = threadIdx.x; k < KCB; k += 256) counts[k] = 0u;
        if (threadIdx.x == 0) { *loss_sum = 0.0; *ovf_cnt = 0u; }
    }
    int tid = blockIdx.x * blockDim.x + threadIdx.x;
    int nth = gridDim.x * blockDim.x;
    int totX = NTOK * DIM / 4;
    for (int i = tid; i < totX; i += nth) {
        float4 v = ((const float4*)X)[i];
        int e0 = i * 4;
        int t = e0 / DIM;
        int d = e0 - t * DIM;
        ushort4 o;
        o.x = f2bf(v.x); o.y = f2bf(v.y); o.z = f2bf(v.z); o.w = f2bf(v.w);
        *(ushort4*)&Xbf[(size_t)t * 1536 + 768 + d] = o;   // byte off: t*3072 + 1536 + 2d
    }
    int totE = KCB * DIM / 4;
    for (int i = tid; i < totE; i += nth) {
        float4 v = ((const float4*)E)[i];
        ushort4 o;
        o.x = f2bf(v.x); o.y = f2bf(v.y); o.z = f2bf(v.z); o.w = f2bf(v.w);
        *(ushort4*)&Ebf[(size_t)i * 4] = o;
    }
}

// K1: split-K main. 512 blocks = 256 token-groups x 2 codebook halves.
// m97 structure: single-buffered LDS (53 KB -> 2 blocks/CU), plain syncthreads.
// Output: per-(token,half) shortlist scratch in the token's out-slot lower half.
__global__ __launch_bounds__(THREADS, 4) void vq_main(
    const unsigned short* __restrict__ Xbf, const unsigned short* __restrict__ Ebf,
    float* __restrict__ out)
{
    __shared__ unsigned short As[BM * BKK];   // 16 KB, swizzled
    __shared__ unsigned short Bs[BN * BKK];   // 16 KB, swizzled
    __shared__ float rowmin4[BM * 4];         // 2 KB
    __shared__ float runmin[BM];
    __shared__ int   cnt[BM];
    __shared__ float candd[BM * CAP];         // 12 KB
    __shared__ unsigned short candk[BM * CAP];// 6 KB

    const int tid = threadIdx.x;
    const int wid = tid >> 6;
    const int lane = tid & 63;
    const int wm = wid >> 2;     // 0..1  (64-token row band)
    const int wn = wid & 3;      // 0..3  (32-code col band)
    const int g = blockIdx.x >> 1;
    const int half = blockIdx.x & 1;
    const int t0 = g * BM;
    const int kofs = half * HALFK;
    const int l15 = lane & 15;
    const int lhi = lane >> 4;

    if (tid < BM) { runmin[tid] = 3.0e38f; cnt[tid] = 0; }
    __syncthreads();

    for (int ci = 0; ci < NCH; ++ci) {
        f32x4 acc[4][2];
        #pragma unroll
        for (int mi = 0; mi < 4; ++mi)
            #pragma unroll
            for (int ni = 0; ni < 2; ++ni) { f32x4 z = {0.f,0.f,0.f,0.f}; acc[mi][ni] = z; }

        const int c0 = ci * BN;   // local code offset within this half

        for (int kb = 0; kb < NKB; ++kb) {
            const int kbb = kb * 128;   // byte offset within a 768-elem bf16 row
            // ---- stage (pre-swizzled global source, linear LDS dest): 4 loads/thread ----
            #pragma unroll
            for (int p = 0; p < 2; ++p) {
                int o = p * 8192 + tid * 16;
                int row = o >> 7, col = o & 127;
                int colsw = col ^ ((row & 7) << 4);
                const char* srcA = (const char*)Xbf + (size_t)(t0 + row) * 3072 + 1536 + kbb + colsw;
                gload_lds16(srcA, (char*)As + o);
                const char* srcB = (const char*)Ebf + (size_t)(kofs + c0 + row) * 1536 + kbb + colsw;
                gload_lds16(srcB, (char*)Bs + o);
            }
            __syncthreads();   // drains vmcnt(0); inter-block overlap hides this (2 blocks/CU)

            #pragma unroll
            for (int ks = 0; ks < 2; ++ks) {
                const int colbase = ks * 64 + lhi * 16;
                bf16x8 a[4], b[2];
                #pragma unroll
                for (int mi = 0; mi < 4; ++mi) {
                    int row = wm * 64 + mi * 16 + l15;
                    int byteoff = row * 128 + (colbase ^ ((row & 7) << 4));
                    a[mi] = *(const bf16x8*)((const char*)As + byteoff);
                }
                #pragma unroll
                for (int ni = 0; ni < 2; ++ni) {
                    int row = wn * 32 + ni * 16 + l15;
                    int byteoff = row * 128 + (colbase ^ ((row & 7) << 4));
                    b[ni] = *(const bf16x8*)((const char*)Bs + byteoff);
                }
                #pragma unroll
                for (int mi = 0; mi < 4; ++mi)
                    #pragma unroll
                    for (int ni = 0; ni < 2; ++ni)
                        acc[mi][ni] = __builtin_amdgcn_mfma_f32_16x16x32_bf16(a[mi], b[ni], acc[mi][ni], 0, 0, 0);
            }
            __syncthreads();   // all reads done -> next stage may overwrite
        }

        // ---- epilogue for this 128-code chunk ----
        #pragma unroll
        for (int mi = 0; mi < 4; ++mi) {
            #pragma unroll
            for (int r = 0; r < 4; ++r) {
                float v = fminf(-2.0f * acc[mi][0][r], -2.0f * acc[mi][1][r]);
                v = fminf(v, __shfl_xor(v, 1, 16));
                v = fminf(v, __shfl_xor(v, 2, 16));
                v = fminf(v, __shfl_xor(v, 4, 16));
                v = fminf(v, __shfl_xor(v, 8, 16));
                if (l15 == 0) {
                    int row = wm * 64 + mi * 16 + lhi * 4 + r;
                    rowmin4[row * 4 + wn] = v;
                }
            }
        }
        __syncthreads();
        if (tid < BM) {
            float m = fminf(fminf(rowmin4[tid*4], rowmin4[tid*4+1]),
                            fminf(rowmin4[tid*4+2], rowmin4[tid*4+3]));
            runmin[tid] = fminf(runmin[tid], m);
        }
        __syncthreads();
        float rm[4][4];
        #pragma unroll
        for (int mi = 0; mi < 4; ++mi)
            #pragma unroll
            for (int r = 0; r < 4; ++r)
                rm[mi][r] = runmin[wm * 64 + mi * 16 + lhi * 4 + r];
        #pragma unroll
        for (int mi = 0; mi < 4; ++mi)
            #pragma unroll
            for (int ni = 0; ni < 2; ++ni)
                #pragma unroll
                for (int r = 0; r < 4; ++r) {
                    float d = -2.0f * acc[mi][ni][r];
                    if (d <= rm[mi][r] + TAU) {
                        int row = wm * 64 + mi * 16 + lhi * 4 + r;
                        int slot = atomicAdd(&cnt[row], 1);
                        if (slot < CAP) {
                            candd[row * CAP + slot] = d;
                            candk[row * CAP + slot] = (unsigned short)(kofs + c0 + wn * 32 + ni * 16 + l15);
                        }
                    }
                }
        __syncthreads();
    }

    // ---- write per-(token,half) scratch into out-slot lower half (38 floats at half*192) ----
    if (tid < BM) {
        int tok = t0 + tid;
        float* base = out + (size_t)tok * DIM + half * 192;
        base[0] = runmin[tid];
        ((int*)base)[1] = cnt[tid];
        #pragma unroll
        for (int s = 0; s < CAP; ++s) base[2 + s] = candd[tid * CAP + s];
        unsigned short* ck = (unsigned short*)(base + 2 + CAP);
        #pragma unroll
        for (int s = 0; s < CAP; ++s) ck[s] = candk[tid * CAP + s];
    }
}

// K2: merge halves, survivor filter, fp64 rescue, outputs. One wave per token.
__global__ __launch_bounds__(THREADS) void vq_final(
    const float* __restrict__ X, const float* __restrict__ Ecb,
    float* __restrict__ out,
    unsigned int* __restrict__ counts, double* __restrict__ loss_sum,
    unsigned int* __restrict__ ovf_cnt, int* __restrict__ ovf_list)
{
    const int wid = threadIdx.x >> 6;
    const int lane = threadIdx.x & 63;
    const int t0 = blockIdx.x * BM;

    for (int i = 0; i < 16; ++i) {
        int tok = t0 + wid * 16 + i;
        const float* b0 = out + (size_t)tok * DIM;
        const float* b1 = b0 + 192;
        float rm = fminf(b0[0], b1[0]);
        int n0 = ((const int*)b0)[1];
        int n1 = ((const int*)b1)[1];
        if (n0 > CAP || n1 > CAP) {
            if (lane == 0) {
                unsigned idx = atomicAdd(ovf_cnt, 1u);
                ovf_list[idx] = tok;
            }
            continue;
        }
        // survivor scan over both lists (lane-uniform broadcast reads)
        int surv = 0, onlyk = 0;
        for (int s = 0; s < n0; ++s)
            if (b0[2 + s] <= rm + TAU) { ++surv; onlyk = ((const unsigned short*)(b0 + 2 + CAP))[s]; }
        for (int s = 0; s < n1; ++s)
            if (b1[2 + s] <= rm + TAU) { ++surv; onlyk = ((const unsigned short*)(b1 + 2 + CAP))[s]; }

        const float4* Xr = (const float4*)&X[(size_t)tok * DIM];
        float4 xv[3];
        #pragma unroll
        for (int j = 0; j < 3; ++j) xv[j] = Xr[j * 64 + lane];

        int bestk;
        if (surv == 1) {
            bestk = onlyk;   // provably the fp32 argmin (all others > TAU - bf16 bound away)
        } else {
            double x2 = 0.0;
            #pragma unroll
            for (int j = 0; j < 3; ++j)
                x2 += (double)xv[j].x * xv[j].x + (double)xv[j].y * xv[j].y
                    + (double)xv[j].z * xv[j].z + (double)xv[j].w * xv[j].w;
            for (int off = 32; off; off >>= 1) x2 += __shfl_down(x2, off);
            x2 = __shfl(x2, 0);
            float x2f = (float)x2;
            float bestt = 3.0e38f; int bk = 1 << 30;
            for (int h = 0; h < 2; ++h) {
                const float* bh = h ? b1 : b0;
                int nh = h ? n1 : n0;
                for (int s = 0; s < nh; ++s) {
                    float dd = bh[2 + s];
                    if (dd > rm + TAU) continue;
                    int k = ((const unsigned short*)(bh + 2 + CAP))[s];
                    const float4* er = (const float4*)&Ecb[(size_t)k * DIM];
                    double dot = 0.0, e2 = 0.0;
                    #pragma unroll
                    for (int j = 0; j < 3; ++j) {
                        float4 ev = er[j * 64 + lane];
                        dot += (double)xv[j].x * ev.x + (double)xv[j].y * ev.y
                             + (double)xv[j].z * ev.z + (double)xv[j].w * ev.w;
                        e2  += (double)ev.x * ev.x + (double)ev.y * ev.y
                             + (double)ev.z * ev.z + (double)ev.w * ev.w;
                    }
                    for (int off = 32; off; off >>= 1) { dot += __shfl_down(dot, off); e2 += __shfl_down(e2, off); }
                    dot = __shfl(dot, 0); e2 = __shfl(e2, 0);
                    float t = x2f - 2.0f * (float)dot;   // reference's fp32 rounding sequence
                    t = t + (float)e2;
                    if (t < bestt || (t == bestt && k < bk)) { bestt = t; bk = k; }
                }
            }
            bestk = bk;
        }
        const float4* q = (const float4*)&Ecb[(size_t)bestk * DIM];
        float4* outr = (float4*)&out[(size_t)tok * DIM];
        double sq = 0.0;
        #pragma unroll
        for (int j = 0; j < 3; ++j) {
            float4 qv = q[j * 64 + lane];
            outr[j * 64 + lane] = qv;
            double d0 = (double)qv.x - xv[j].x, d1 = (double)qv.y - xv[j].y;
            double d2 = (double)qv.z - xv[j].z, d3 = (double)qv.w - xv[j].w;
            sq += d0 * d0 + d1 * d1 + d2 * d2 + d3 * d3;
        }
        for (int off = 32; off; off >>= 1) sq += __shfl_down(sq, off);
        if (lane == 0) {
            out[(size_t)NTOK * DIM + tok] = (float)bestk;
            atomicAdd(&counts[bestk], 1u);
            atomicAdd(loss_sum, sq);
        }
    }
}

// K3: brute-force rescue for shortlist-overflow tokens. Wave-per-token, lanes over dims,
// coalesced float4 codebook reads, fp64 shuffle-reduce per code. Expected tokens ~0.
__global__ __launch_bounds__(256) void vq_overflow(
    const float* __restrict__ X, const float* __restrict__ Ecb,
    float* __restrict__ out, unsigned int* __restrict__ counts,
    double* __restrict__ loss_sum,
    const unsigned int* __restrict__ ovf_cnt, const int* __restrict__ ovf_list)
{
    int n = (int)*ovf_cnt;
    if (n == 0) return;
    const int lane = threadIdx.x & 63;
    const int gwave = (blockIdx.x * 256 + threadIdx.x) >> 6;
    const int nwave = (gridDim.x * 256) >> 6;

    for (int ti = gwave; ti < n; ti += nwave) {
        int tok = ovf_list[ti];
        const float4* Xr = (const float4*)&X[(size_t)tok * DIM];
        float4 xv[3];
        #pragma unroll
        for (int j = 0; j < 3; ++j) xv[j] = Xr[j * 64 + lane];
        double x2 = 0.0;
        #pragma unroll
        for (int j = 0; j < 3; ++j)
            x2 += (double)xv[j].x * xv[j].x + (double)xv[j].y * xv[j].y
                + (double)xv[j].z * xv[j].z + (double)xv[j].w * xv[j].w;
        for (int off = 32; off; off >>= 1) x2 += __shfl_down(x2, off);
        x2 = __shfl(x2, 0);
        float x2f = (float)x2;

        float bestt = 3.0e38f; int bestk = 1 << 30;
        for (int k = 0; k < KCB; ++k) {
            const float4* er = (const float4*)&Ecb[(size_t)k * DIM];
            double dot = 0.0, e2 = 0.0;
            #pragma unroll
            for (int j = 0; j < 3; ++j) {
                float4 ev = er[j * 64 + lane];
                dot += (double)xv[j].x * ev.x + (double)xv[j].y * ev.y
                     + (double)xv[j].z * ev.z + (double)xv[j].w * ev.w;
                e2  += (double)ev.x * ev.x + (double)ev.y * ev.y
                     + (double)ev.z * ev.z + (double)ev.w * ev.w;
            }
            for (int off = 32; off; off >>= 1) { dot += __shfl_down(dot, off); e2 += __shfl_down(e2, off); }
            dot = __shfl(dot, 0); e2 = __shfl(e2, 0);
            float t = x2f - 2.0f * (float)dot;
            t = t + (float)e2;
            if (t < bestt || (t == bestt && k < bestk)) { bestt = t; bestk = k; }
        }

        const float4* q = (const float4*)&Ecb[(size_t)bestk * DIM];
        float4* outr = (float4*)&out[(size_t)tok * DIM];
        double sq = 0.0;
        #pragma unroll
        for (int j = 0; j < 3; ++j) {
            float4 qv = q[j * 64 + lane];
            outr[j * 64 + lane] = qv;
            double d0 = (double)qv.x - xv[j].x, d1 = (double)qv.y - xv[j].y;
            double d2 = (double)qv.z - xv[j].z, d3 = (double)qv.w - xv[j].w;
            sq += d0 * d0 + d1 * d1 + d2 * d2 + d3 * d3;
        }
        for (int off = 32; off; off >>= 1) sq += __shfl_down(sq, off);
        if (lane == 0) {
            out[(size_t)NTOK * DIM + tok] = (float)bestk;
            atomicAdd(&counts[bestk], 1u);
            atomicAdd(loss_sum, sq);
        }
    }
}

// K4: scalars (loss/commitment/codebook/perplexity/usage)
__global__ void vq_stats(const unsigned int* __restrict__ counts, const double* __restrict__ loss_sum,
                         float* __restrict__ out)
{
    __shared__ double hred[256];
    __shared__ int ured[256];
    double h = 0.0; int used = 0;
    for (int k = threadIdx.x; k < KCB; k += 256) {
        unsigned c = counts[k];
        double pr = (double)c / (double)NTOK;
        h -= pr * log(pr + 1e-10);
        used += (c > 0) ? 1 : 0;
    }
    hred[threadIdx.x] = h; ured[threadIdx.x] = used; __syncthreads();
    for (int s = 128; s; s >>= 1) {
        if (threadIdx.x < s) { hred[threadIdx.x] += hred[threadIdx.x + s]; ured[threadIdx.x] += ured[threadIdx.x + s]; }
        __syncthreads();
    }
    if (threadIdx.x == 0) {
        double S = *loss_sum;
        double mse = S / ((double)NTOK * (double)DIM);
        size_t base = (size_t)NTOK * DIM + NTOK;
        out[base + 0] = (float)(mse * 1.25);   // loss = codebook + 0.25*commitment
        out[base + 1] = (float)mse;            // commitment_loss
        out[base + 2] = (float)mse;            // codebook_loss
        out[base + 3] = (float)exp(hred[0]);   // perplexity
        out[base + 4] = (float)((double)ured[0] / (double)KCB);  // usage_rate
    }
}

extern "C" void kernel_launch(void* const* d_in, const int* in_sizes, int n_in,
                              void* d_out, int out_size, void* d_ws, size_t ws_size,
                              hipStream_t stream) {
    const float* X = (const float*)d_in[0];
    const float* E = (const float*)d_in[1];
    float* out = (float*)d_out;
    char* ws = (char*)d_ws;
    unsigned short* Ebf = (unsigned short*)ws;                 // 6,291,456 B
    unsigned int* counts = (unsigned int*)(ws + 6291456);      // 16,384 B
    double* loss_sum = (double*)(ws + 6307840);                // 8 B
    unsigned int* ovf_cnt = (unsigned int*)(ws + 6307848);     // 4 B (+4 pad)
    int* ovf_list = (int*)(ws + 6307856);                      // 131,072 B
    unsigned short* Xbf = (unsigned short*)d_out;              // bf16 stash in out-slot upper halves

    vq_convert<<<2048, 256, 0, stream>>>(X, E, Xbf, Ebf, counts, loss_sum, ovf_cnt);
    vq_main<<<2 * (NTOK / BM), THREADS, 0, stream>>>(Xbf, Ebf, out);
    vq_final<<<NTOK / BM, THREADS, 0, stream>>>(X, E, out, counts, loss_sum, ovf_cnt, ovf_list);
    vq_overflow<<<256, 256, 0, stream>>>(X, E, out, counts, loss_sum, ovf_cnt, ovf_list);
    vq_stats<<<1, 256, 0, stream>>>(counts, loss_sum, out);
}